// Round 1
// baseline (284.279 us; speedup 1.0000x reference)
//
#include <hip/hip_runtime.h>
#include <stdint.h>

#define Bsz   16384
#define Tt    79
#define Hh    256
#define Dd    256
#define KP    288    // padded K: 256 h-cols + 3 x rows + 1 bias row + 28 zero pad
#define LROW  296    // LDS row stride in bf16 elements (592 B = 37 x 16B granules)
#define NTILE 64     // batch rows per block

typedef __attribute__((ext_vector_type(8))) short  short8;
typedef __attribute__((ext_vector_type(4))) float  float4_;

__device__ __forceinline__ unsigned short f2bf(float f){
  unsigned u = __float_as_uint(f);
  u += 0x7fffu + ((u >> 16) & 1u);      // RNE
  return (unsigned short)(u >> 16);
}
__device__ __forceinline__ unsigned pk2(float a, float b){
  return (unsigned)f2bf(a) | ((unsigned)f2bf(b) << 16);
}

// Build bf16 tables in workspace:
//   Ut  (256 x 288): Ut[m][k] = U[k][m] (k<256), W_in[k-256][m] (k=256..258),
//                    b_rnn[m] (k=259), 0 otherwise
//   Wdt (256 x 288): Wdt[m][k] = W_d[k][m] (k<256), b_d[m] (k=259), 0 otherwise
__global__ void build_tables(const float* __restrict__ W_in,
                             const float* __restrict__ U,
                             const float* __restrict__ b_rnn,
                             const float* __restrict__ W_d,
                             const float* __restrict__ b_d,
                             unsigned short* __restrict__ Ut,
                             unsigned short* __restrict__ Wdt){
  const int TBL = 256 * KP;
  int idx = blockIdx.x * 256 + threadIdx.x;
  if (idx >= 2 * TBL) return;
  int tb  = idx / TBL;
  int rem = idx - tb * TBL;
  int m = rem / KP;
  int k = rem - m * KP;
  float v = 0.f;
  if (tb == 0){
    if      (k < 256) v = U[k * 256 + m];
    else if (k < 259) v = W_in[(k - 256) * 256 + m];
    else if (k == 259) v = b_rnn[m];
  } else {
    if      (k < 256) v = W_d[k * 256 + m];
    else if (k == 259) v = b_d[m];
  }
  unsigned short o = f2bf(v);
  if (tb == 0) Ut[rem] = o; else Wdt[rem] = o;
}

// Persistent recurrence kernel: 256 blocks x 256 threads, 1 block/CU.
// Each block owns 64 batch rows; h^T (64 x 288 bf16) lives in LDS; U^T lives
// in per-wave A-fragment registers. Wave grid 2(m) x 2(n):
//   wave m-half = 128 h-cols (8 MFMA tiles), wave n-half = 32 batch rows (2 tiles).
__global__ __launch_bounds__(256, 1) void rnn_main(
    const float* __restrict__ x0,
    const float* __restrict__ x1,
    const float* __restrict__ x2,
    const unsigned short* __restrict__ Ut,
    const unsigned short* __restrict__ Wdt,
    float* __restrict__ out){
  __shared__ __align__(16) short hbuf[NTILE * LROW];

  const int tid  = threadIdx.x;
  const int lane = tid & 63;
  const int wave = tid >> 6;
  const int wm   = wave >> 1;   // m-half 0/1
  const int wn   = wave & 1;    // n-half 0/1
  const int quad = lane >> 4;
  const int ln   = lane & 15;
  const int bbase = blockIdx.x * NTILE;

  // ---- init: zero the whole LDS buffer (covers zero pad rows + h0 = 0) ----
  {
    int4* p = (int4*)hbuf;
    const int tot = NTILE * LROW * 2 / 16;  // 2368 int4
    int4 z = make_int4(0, 0, 0, 0);
    for (int i = tid; i < tot; i += 256) p[i] = z;
  }
  __syncthreads();

  // bias row (k = 259) = 1.0 bf16, written once
  if (tid < NTILE) hbuf[tid * LROW + 259] = (short)0x3F80;

  // x rows for step t = 0 (original time index T-1)
  const bool stager = (wm == 0) && (lane < 32);
  const int  sn  = wn * 32 + lane;         // 0..63 among stagers
  const int  sgb = bbase + sn;
  if (stager){
    int tr = Tt - 1;
    float a = x0[sgb * Tt + tr];
    float b = x1[sgb * Tt + tr];
    float c = x2[sgb * Tt + tr];
    *(unsigned*)&hbuf[sn * LROW + 256] = pk2(a, b);
    hbuf[sn * LROW + 258] = (short)f2bf(c);
  }

  // ---- preload A fragments: U^T (+W_in, b_rnn) -> 72 x short8 = 288 VGPRs ----
  short8 afr[8][9];
  #pragma unroll
  for (int mt = 0; mt < 8; ++mt){
    int m = wm * 128 + mt * 16 + ln;
    #pragma unroll
    for (int kt = 0; kt < 9; ++kt){
      afr[mt][kt] = *(const short8*)(Ut + m * KP + kt * 32 + quad * 8);
    }
  }
  __syncthreads();

  const float4_ zz = {0.f, 0.f, 0.f, 0.f};
  float4_ acc[8][2];

  // ---- 79 recurrence steps ----
  #pragma unroll 1
  for (int t = 0; t < Tt; ++t){
    // prefetch x for step t+1 (global, latency hidden under the k-loop)
    float xa = 0.f, xb = 0.f, xc = 0.f;
    if (stager && t < Tt - 1){
      int tr = Tt - 2 - t;
      xa = x0[sgb * Tt + tr];
      xb = x1[sgb * Tt + tr];
      xc = x2[sgb * Tt + tr];
    }

    // K-loop: acc[m][n] = sum_k Ut[m][k] * h^T[k][n]  (x + bias rows folded in)
    #pragma unroll
    for (int kt = 0; kt < 9; ++kt){
      short8 bf0 = *(const short8*)&hbuf[(wn * 32 +  0 + ln) * LROW + kt * 32 + quad * 8];
      short8 bf1 = *(const short8*)&hbuf[(wn * 32 + 16 + ln) * LROW + kt * 32 + quad * 8];
      #pragma unroll
      for (int mt = 0; mt < 8; ++mt){
        if (kt == 0){
          acc[mt][0] = __builtin_amdgcn_mfma_f32_16x16x32_bf16(afr[mt][0], bf0, zz, 0, 0, 0);
          acc[mt][1] = __builtin_amdgcn_mfma_f32_16x16x32_bf16(afr[mt][0], bf1, zz, 0, 0, 0);
        } else {
          acc[mt][0] = __builtin_amdgcn_mfma_f32_16x16x32_bf16(afr[mt][kt], bf0, acc[mt][0], 0, 0, 0);
          acc[mt][1] = __builtin_amdgcn_mfma_f32_16x16x32_bf16(afr[mt][kt], bf1, acc[mt][1], 0, 0, 0);
        }
      }
    }

    // relu + pack to bf16 pairs (before barrier: no LDS touched)
    unsigned w0[8][2], w1[8][2];
    #pragma unroll
    for (int mt = 0; mt < 8; ++mt){
      #pragma unroll
      for (int nt = 0; nt < 2; ++nt){
        float4_ v = acc[mt][nt];
        w0[mt][nt] = pk2(fmaxf(v[0], 0.f), fmaxf(v[1], 0.f));
        w1[mt][nt] = pk2(fmaxf(v[2], 0.f), fmaxf(v[3], 0.f));
      }
    }

    __syncthreads();   // all waves done reading h(t)

    // write h(t+1): C/D layout gives 4 consecutive h-cols per lane -> b64
    #pragma unroll
    for (int mt = 0; mt < 8; ++mt){
      #pragma unroll
      for (int nt = 0; nt < 2; ++nt){
        int n = wn * 32 + nt * 16 + ln;
        int m = wm * 128 + mt * 16 + quad * 4;
        uint2 w; w.x = w0[mt][nt]; w.y = w1[mt][nt];
        *(uint2*)&hbuf[n * LROW + m] = w;
      }
    }
    // x rows for step t+1
    if (stager && t < Tt - 1){
      *(unsigned*)&hbuf[sn * LROW + 256] = pk2(xa, xb);
      hbuf[sn * LROW + 258] = (short)f2bf(xc);
    }

    __syncthreads();   // h(t+1) visible before next step's reads
  }

  // ---- epilogue: out^T = W_d^T h^T + b_d (bias row k=259 still 1.0) ----
  float4_ oacc[8][2];
  #pragma unroll
  for (int kt = 0; kt < 9; ++kt){
    short8 wf[8];
    #pragma unroll
    for (int mt = 0; mt < 8; ++mt){
      int m = wm * 128 + mt * 16 + ln;
      wf[mt] = *(const short8*)(Wdt + m * KP + kt * 32 + quad * 8);
    }
    short8 bf0 = *(const short8*)&hbuf[(wn * 32 +  0 + ln) * LROW + kt * 32 + quad * 8];
    short8 bf1 = *(const short8*)&hbuf[(wn * 32 + 16 + ln) * LROW + kt * 32 + quad * 8];
    #pragma unroll
    for (int mt = 0; mt < 8; ++mt){
      if (kt == 0){
        oacc[mt][0] = __builtin_amdgcn_mfma_f32_16x16x32_bf16(wf[mt], bf0, zz, 0, 0, 0);
        oacc[mt][1] = __builtin_amdgcn_mfma_f32_16x16x32_bf16(wf[mt], bf1, zz, 0, 0, 0);
      } else {
        oacc[mt][0] = __builtin_amdgcn_mfma_f32_16x16x32_bf16(wf[mt], bf0, oacc[mt][0], 0, 0, 0);
        oacc[mt][1] = __builtin_amdgcn_mfma_f32_16x16x32_bf16(wf[mt], bf1, oacc[mt][1], 0, 0, 0);
      }
    }
  }

  // store: lane holds 4 consecutive d at fixed batch row -> float4 store
  #pragma unroll
  for (int mt = 0; mt < 8; ++mt){
    #pragma unroll
    for (int nt = 0; nt < 2; ++nt){
      int n = wn * 32 + nt * 16 + ln;
      int m = wm * 128 + mt * 16 + quad * 4;
      *(float4_*)&out[(bbase + n) * Dd + m] = oacc[mt][nt];
    }
  }
}

extern "C" void kernel_launch(void* const* d_in, const int* in_sizes, int n_in,
                              void* d_out, int out_size, void* d_ws, size_t ws_size,
                              hipStream_t stream){
  const float* x0    = (const float*)d_in[0];
  const float* x1    = (const float*)d_in[1];
  const float* x2    = (const float*)d_in[2];
  const float* W_in  = (const float*)d_in[3];
  const float* U     = (const float*)d_in[4];
  const float* b_rnn = (const float*)d_in[5];
  const float* W_d   = (const float*)d_in[6];
  const float* b_d   = (const float*)d_in[7];

  unsigned short* Ut  = (unsigned short*)d_ws;
  unsigned short* Wdt = Ut + 256 * KP;
  float* out = (float*)d_out;

  build_tables<<<(2 * 256 * KP + 255) / 256, 256, 0, stream>>>(W_in, U, b_rnn, W_d, b_d, Ut, Wdt);
  rnn_main<<<Bsz / NTILE, 256, 0, stream>>>(x0, x1, x2, Ut, Wdt, out);
}